// Round 1
// baseline (133.685 us; speedup 1.0000x reference)
//
#include <hip/hip_runtime.h>
#include <math.h>

#define R 2048
#define C 1024
#define CH 8
#define BA 8
#define K 64  // CH*BA

// Output layout (floats), concatenated in reference return order:
#define OFF_P     0
#define OFF_TOT   (R*K)            // 131072
#define OFF_MAX   (OFF_TOT + 8)    // 131080
#define OFF_NCOL  (OFF_MAX + 8)    // 131088
#define OFF_NROW  (OFF_NCOL + 8)   // 131096
#define OFF_NNZ   (OFF_NROW + 8)   // 131104
#define OFF_DEN   (OFF_NNZ + 64)   // 131168
#define OFF_SEL   (OFF_DEN + 8)    // 131176

// ws layout (floats): [0, R*CH) = q[r][ch]; then accumulators:
//   acc[0..63]  nnz_ch_ba
//   acc[64..71] num_row_ch
//   acc[72..79] num_col_ch
//   acc[80]     num_row_sel

__global__ void init_acc_kernel(float* __restrict__ acc) {
    int t = threadIdx.x;
    if (t < 81) acc[t] = 0.0f;
}

__global__ __launch_bounds__(256) void rows_kernel(
    const float* __restrict__ W, const float* __restrict__ D,
    const float* __restrict__ g, float* __restrict__ P,
    float* __restrict__ q, float* __restrict__ acc)
{
    const int tid  = threadIdx.x;
    const int lane = tid & 63;
    const int w    = tid >> 6;           // wave id within block, 0..3

    float acc_nnz  = 0.0f;               // per-thread: (ch,ba) = lane
    float acc_srow = 0.0f;               // valid on lanes with (lane&7)==0
    float acc_sel  = 0.0f;               // valid on lane 0

    #pragma unroll
    for (int it = 0; it < 4; ++it) {
        const int row = blockIdx.x * 16 + it * 4 + w;

        // ---- softmax over 64 logits (one wave == one row) ----
        float z = W[row * K + lane] + g[row * K + lane];
        float m = z;
        #pragma unroll
        for (int off = 32; off >= 1; off >>= 1)
            m = fmaxf(m, __shfl_xor(m, off, 64));
        float e = expf(z - m);
        float s = e;
        #pragma unroll
        for (int off = 32; off >= 1; off >>= 1)
            s += __shfl_xor(s, off, 64);
        float p = e / s;
        P[row * K + lane] = p;

        // ---- rowsum of D (coalesced float4) ----
        const float4* Drow = (const float4*)(D + (size_t)row * C);
        float ds = 0.0f;
        #pragma unroll
        for (int k2 = 0; k2 < 4; ++k2) {
            float4 v = Drow[lane + 64 * k2];
            ds += (v.x + v.y) + (v.z + v.w);
        }
        #pragma unroll
        for (int off = 32; off >= 1; off >>= 1)
            ds += __shfl_xor(ds, off, 64);

        acc_nnz += p * ds;

        // ---- row max for num_row_sel ----
        float pm = p;
        #pragma unroll
        for (int off = 32; off >= 1; off >>= 1)
            pm = fmaxf(pm, __shfl_xor(pm, off, 64));
        if (lane == 0 && pm > 0.99f) acc_sel += 1.0f;

        // ---- per-channel sum and product-of-(1-p) within groups of 8 ----
        float sc = p;
        float om = 1.0f - p;
        #pragma unroll
        for (int off = 1; off <= 4; off <<= 1) {
            sc += __shfl_xor(sc, off, 64);
            om *= __shfl_xor(om, off, 64);
        }
        if ((lane & 7) == 0) {
            q[row * CH + (lane >> 3)] = om;
            acc_srow += sc;
        }
    }

    // ---- block reduction then atomics ----
    __shared__ float redN[4][64];
    __shared__ float redS[4][8];
    __shared__ float redSel[4];
    redN[w][lane] = acc_nnz;
    if ((lane & 7) == 0) redS[w][lane >> 3] = acc_srow;
    if (lane == 0) redSel[w] = acc_sel;
    __syncthreads();

    if (w == 0) {
        float v = redN[0][lane] + redN[1][lane] + redN[2][lane] + redN[3][lane];
        atomicAdd(&acc[lane], v);
    }
    if (tid < 8) {
        float v = redS[0][tid] + redS[1][tid] + redS[2][tid] + redS[3][tid];
        atomicAdd(&acc[64 + tid], v);
    }
    if (tid == 0) {
        atomicAdd(&acc[80], redSel[0] + redSel[1] + redSel[2] + redSel[3]);
    }
}

__global__ __launch_bounds__(256) void cols_kernel(
    const float* __restrict__ D, const float* __restrict__ q,
    float* __restrict__ acc)
{
    const int tid  = threadIdx.x;
    const int lane = tid & 63;
    const int w    = tid >> 6;                 // row-quarter 0..3
    const int col  = blockIdx.x * 64 + lane;   // 16 blocks x 64 cols

    float pr[8];
    #pragma unroll
    for (int ch = 0; ch < 8; ++ch) pr[ch] = 1.0f;

    const int r0 = w * (R / 4);
    #pragma unroll 4
    for (int r = r0; r < r0 + (R / 4); ++r) {
        float d = D[(size_t)r * C + col];
        const float4* qr = (const float4*)(q + r * CH);
        float4 q0 = qr[0];
        float4 q1 = qr[1];
        pr[0] *= fmaf(d, q0.x - 1.0f, 1.0f);
        pr[1] *= fmaf(d, q0.y - 1.0f, 1.0f);
        pr[2] *= fmaf(d, q0.z - 1.0f, 1.0f);
        pr[3] *= fmaf(d, q0.w - 1.0f, 1.0f);
        pr[4] *= fmaf(d, q1.x - 1.0f, 1.0f);
        pr[5] *= fmaf(d, q1.y - 1.0f, 1.0f);
        pr[6] *= fmaf(d, q1.z - 1.0f, 1.0f);
        pr[7] *= fmaf(d, q1.w - 1.0f, 1.0f);
    }

    __shared__ float part[4][64][8];
    #pragma unroll
    for (int ch = 0; ch < 8; ++ch) part[w][lane][ch] = pr[ch];
    __shared__ float sums[8];
    if (tid < 8) sums[tid] = 0.0f;
    __syncthreads();

    {
        int ch = tid & 7;
        float local = 0.0f;
        #pragma unroll
        for (int cc = tid >> 3; cc < 64; cc += 32) {
            float v = part[0][cc][ch] * part[1][cc][ch] *
                      part[2][cc][ch] * part[3][cc][ch];
            local += 1.0f - v;
        }
        atomicAdd(&sums[ch], local);
    }
    __syncthreads();
    if (tid < 8) atomicAdd(&acc[72 + tid], sums[tid]);
}

__global__ void finalize_kernel(const float* __restrict__ acc,
                                float* __restrict__ out)
{
    const int lane = threadIdx.x;  // 64 threads, lane = ch*8+ba
    float nnzv = acc[lane];
    out[OFF_NNZ + lane] = nnzv;

    float sum = nnzv, mx = nnzv;
    #pragma unroll
    for (int off = 1; off <= 4; off <<= 1) {
        sum += __shfl_xor(sum, off, 64);
        mx = fmaxf(mx, __shfl_xor(mx, off, 64));
    }
    if ((lane & 7) == 0) {
        int ch = lane >> 3;
        float nr = acc[64 + ch];
        float nc = acc[72 + ch];
        out[OFF_TOT  + ch] = mx + nc + nr;
        out[OFF_MAX  + ch] = mx;
        out[OFF_NCOL + ch] = nc;
        out[OFF_NROW + ch] = nr;
        out[OFF_DEN  + ch] = sum / nr / nc;
    }
    if (lane == 0) out[OFF_SEL] = acc[80];
}

extern "C" void kernel_launch(void* const* d_in, const int* in_sizes, int n_in,
                              void* d_out, int out_size, void* d_ws, size_t ws_size,
                              hipStream_t stream) {
    const float* W = (const float*)d_in[0];
    const float* D = (const float*)d_in[1];
    const float* g = (const float*)d_in[2];
    // d_in[3] is `i`, unused by the math.
    float* out = (float*)d_out;
    float* q   = (float*)d_ws;
    float* acc = q + R * CH;

    init_acc_kernel<<<1, 128, 0, stream>>>(acc);
    rows_kernel<<<R / 16, 256, 0, stream>>>(W, D, g, out, q, acc);
    cols_kernel<<<C / 64, 256, 0, stream>>>(D, q, acc);
    finalize_kernel<<<1, 64, 0, stream>>>(acc, out);
}

// Round 2
// 81.233 us; speedup vs baseline: 1.6457x; 1.6457x over previous
//
#include <hip/hip_runtime.h>
#include <math.h>

#define R 2048
#define C 1024
#define CH 8
#define K 64  // CH*BA

// Output layout (floats), reference return order:
#define OFF_P     0
#define OFF_TOT   (R*K)            // 131072
#define OFF_MAX   (OFF_TOT + 8)
#define OFF_NCOL  (OFF_MAX + 8)
#define OFF_NROW  (OFF_NCOL + 8)
#define OFF_NNZ   (OFF_NROW + 8)
#define OFF_DEN   (OFF_NNZ + 64)
#define OFF_SEL   (OFF_DEN + 8)

// ws layout (floats):
#define WS_LQ   0              // lq2[R][CH]   = log2 of per-(row,ch) prod(1-p)
#define WS_RS   16384          // rowsum[R]    = per-row sum of D
#define WS_COL  18432          // colsum[C*CH] = masked log2 sums (atomic)
#define WS_ACC  26624          // acc[137]: [0..63] nnz, [64..127] psum,
                               //           [128..135] ncol, [136] sel

// ---------------------------------------------------------------- kernel A
// One row per wave. Softmax, P, lq2, rowsumD. Also zero-inits accumulators.
__global__ __launch_bounds__(256) void kA(
    const float* __restrict__ W, const float* __restrict__ D,
    const float* __restrict__ g, float* __restrict__ P,
    float* __restrict__ ws)
{
    const int tid  = threadIdx.x;
    const int lane = tid & 63;
    const int w    = tid >> 6;

    // zero accumulators (consumed only by kB/kC, which run after A)
    if (blockIdx.x == 0 && tid < 137) ws[WS_ACC + tid] = 0.0f;
    if (blockIdx.x < 32) ws[WS_COL + blockIdx.x * 256 + tid] = 0.0f;

    const int row = blockIdx.x * 4 + w;

    float z = W[row * K + lane] + g[row * K + lane];
    float m = z;
    #pragma unroll
    for (int off = 32; off >= 1; off >>= 1)
        m = fmaxf(m, __shfl_xor(m, off, 64));
    float e = expf(z - m);
    float s = e;
    #pragma unroll
    for (int off = 32; off >= 1; off >>= 1)
        s += __shfl_xor(s, off, 64);
    float p = e / s;
    P[row * K + lane] = p;

    // per-channel product of (1-p) within 8-lane groups
    float om = 1.0f - p;
    #pragma unroll
    for (int off = 1; off <= 4; off <<= 1)
        om *= __shfl_xor(om, off, 64);
    if ((lane & 7) == 0)
        ws[WS_LQ + row * CH + (lane >> 3)] = log2f(om);

    // rowsum of D (coalesced float4)
    const float4* Drow = (const float4*)(D + (size_t)row * C);
    float ds = 0.0f;
    #pragma unroll
    for (int k2 = 0; k2 < 4; ++k2) {
        float4 v = Drow[lane + 64 * k2];
        ds += (v.x + v.y) + (v.z + v.w);
    }
    #pragma unroll
    for (int off = 32; off >= 1; off >>= 1)
        ds += __shfl_xor(ds, off, 64);
    if (lane == 0) ws[WS_RS + row] = ds;
}

// ---------------------------------------------------------------- kernel B
// 256 blocks: 16 col-tiles x 16 row-chunks. Masked log2 sums -> colsum.
__global__ __launch_bounds__(256) void kB(
    const float* __restrict__ D, float* __restrict__ ws)
{
    const int tid  = threadIdx.x;
    const int lane = tid & 63;
    const int w    = tid >> 6;
    const int cb   = blockIdx.x & 15;
    const int rc   = blockIdx.x >> 4;

    __shared__ float ldsq[128 * CH];      // this chunk's 128 rows of lq2
    ((float4*)ldsq)[tid] = ((const float4*)(ws + WS_LQ + rc * 128 * CH))[tid];
    __shared__ float part[4][64][9];      // +1 pad: conflict-free
    __syncthreads();

    const int col = cb * 64 + lane;
    float s0=0,s1=0,s2=0,s3=0,s4=0,s5=0,s6=0,s7=0;

    const int r0 = w * 32;
    #pragma unroll 4
    for (int i = 0; i < 32; ++i) {
        const int rl = r0 + i;
        float d = D[(size_t)(rc * 128 + rl) * C + col];
        const float* lr = ldsq + rl * CH;   // wave-uniform -> broadcast
        s0 += d * lr[0]; s1 += d * lr[1]; s2 += d * lr[2]; s3 += d * lr[3];
        s4 += d * lr[4]; s5 += d * lr[5]; s6 += d * lr[6]; s7 += d * lr[7];
    }
    part[w][lane][0]=s0; part[w][lane][1]=s1; part[w][lane][2]=s2; part[w][lane][3]=s3;
    part[w][lane][4]=s4; part[w][lane][5]=s5; part[w][lane][6]=s6; part[w][lane][7]=s7;
    __syncthreads();

    #pragma unroll
    for (int ps = 0; ps < 2; ++ps) {
        int flat = ps * 256 + tid;          // [0,512): 64 cols x 8 ch
        int cl = flat >> 3, ch = flat & 7;
        float v = part[0][cl][ch] + part[1][cl][ch] +
                  part[2][cl][ch] + part[3][cl][ch];
        atomicAdd(&ws[WS_COL + (cb * 64 + cl) * CH + ch], v);
    }
}

// ---------------------------------------------------------------- kernel C
// blocks 0..31: P-derived reductions (nnz, psum, sel). blocks 32..39: num_col.
__global__ __launch_bounds__(256) void kC(
    const float* __restrict__ P, float* __restrict__ ws)
{
    const int tid  = threadIdx.x;
    const int lane = tid & 63;
    const int w    = tid >> 6;
    const int b    = blockIdx.x;
    float* acc = ws + WS_ACC;

    if (b < 32) {
        const float* rowsum = ws + WS_RS;
        float nnz_l = 0.0f, ps_l = 0.0f, sel_l = 0.0f;
        #pragma unroll 4
        for (int i = 0; i < 16; ++i) {
            const int r = b * 64 + i * 4 + w;
            float p  = P[r * K + lane];
            float rs = rowsum[r];
            nnz_l += p * rs;
            ps_l  += p;
            float pm = p;
            #pragma unroll
            for (int off = 32; off >= 1; off >>= 1)
                pm = fmaxf(pm, __shfl_xor(pm, off, 64));
            if (lane == 0 && pm > 0.99f) sel_l += 1.0f;
        }
        __shared__ float rn[4][64], rp[4][64], rsel[4];
        rn[w][lane] = nnz_l;
        rp[w][lane] = ps_l;
        if (lane == 0) rsel[w] = sel_l;
        __syncthreads();
        if (w == 0) {
            atomicAdd(&acc[lane],      rn[0][lane]+rn[1][lane]+rn[2][lane]+rn[3][lane]);
            atomicAdd(&acc[64 + lane], rp[0][lane]+rp[1][lane]+rp[2][lane]+rp[3][lane]);
        }
        if (tid == 0)
            atomicAdd(&acc[136], rsel[0]+rsel[1]+rsel[2]+rsel[3]);
    } else {
        const int cb = b - 32;  // 0..7, 128 cols each
        const float* colsum = ws + WS_COL;
        float ncol_l = 0.0f;
        #pragma unroll
        for (int ps = 0; ps < 4; ++ps) {
            int flat = cb * 1024 + ps * 256 + tid;
            ncol_l += 1.0f - exp2f(colsum[flat]);
        }
        __shared__ float nc[256];
        nc[tid] = ncol_l;
        __syncthreads();
        for (int off = 128; off >= 8; off >>= 1) {
            if (tid < off) nc[tid] += nc[tid + off];
            __syncthreads();
        }
        if (tid < 8) atomicAdd(&acc[128 + tid], nc[tid]);
    }
}

// ---------------------------------------------------------------- kernel D
__global__ void kD(const float* __restrict__ ws, float* __restrict__ out)
{
    const float* acc = ws + WS_ACC;
    const int lane = threadIdx.x;  // 64 threads, lane = ch*8+ba

    float nnzv = acc[lane];
    out[OFF_NNZ + lane] = nnzv;

    float sum = nnzv, mx = nnzv;
    float pv = acc[64 + lane];
    #pragma unroll
    for (int off = 1; off <= 4; off <<= 1) {
        sum += __shfl_xor(sum, off, 64);
        mx = fmaxf(mx, __shfl_xor(mx, off, 64));
        pv += __shfl_xor(pv, off, 64);
    }
    if ((lane & 7) == 0) {
        int ch = lane >> 3;
        float nr = pv;
        float nc = acc[128 + ch];
        out[OFF_TOT  + ch] = mx + nc + nr;
        out[OFF_MAX  + ch] = mx;
        out[OFF_NCOL + ch] = nc;
        out[OFF_NROW + ch] = nr;
        out[OFF_DEN  + ch] = sum / nr / nc;
    }
    if (lane == 0) out[OFF_SEL] = acc[136];
}

extern "C" void kernel_launch(void* const* d_in, const int* in_sizes, int n_in,
                              void* d_out, int out_size, void* d_ws, size_t ws_size,
                              hipStream_t stream) {
    const float* W = (const float*)d_in[0];
    const float* D = (const float*)d_in[1];
    const float* g = (const float*)d_in[2];
    float* out = (float*)d_out;
    float* ws  = (float*)d_ws;

    kA<<<R / 4, 256, 0, stream>>>(W, D, g, out, ws);
    kB<<<256,   256, 0, stream>>>(D, ws);
    kC<<<40,    256, 0, stream>>>(out, ws);
    kD<<<1,      64, 0, stream>>>(ws, out);
}